// Round 1
// baseline (215.936 us; speedup 1.0000x reference)
//
#include <hip/hip_runtime.h>
#include <hip/hip_bf16.h>

#define NUM_RHS_EMB 100000
#define NUM_TYPES   64
#define NUM_LHS_EMB 100000
#define NR 8192   // rhs idxs -> output cols
#define NL 8192   // lhs idxs -> output rows

typedef __attribute__((ext_vector_type(8))) short short8;
typedef __attribute__((ext_vector_type(4))) float f32x4;

__device__ __forceinline__ ushort f2b(float x) {
    unsigned u = __builtin_bit_cast(unsigned, x);
    unsigned r = u + 0x7fffu + ((u >> 16) & 1u);   // RNE-ish
    return (ushort)(r >> 16);
}

// ---------------- Kernel A: LSE_k = log sum_j exp(t[k][j] + bias[j]) ----------------
__global__ __launch_bounds__(256) void lse_kernel(
    const float* __restrict__ t, const float* __restrict__ bias, float* __restrict__ lse) {
    const int k = blockIdx.x;
    const float* __restrict__ row = t + (size_t)k * NUM_LHS_EMB;
    __shared__ float red[4];
    const int tid = threadIdx.x, w = tid >> 6;

    float m = -1e30f;
    for (int j = tid; j < NUM_LHS_EMB; j += 256) m = fmaxf(m, row[j] + bias[j]);
    #pragma unroll
    for (int d = 1; d < 64; d <<= 1) m = fmaxf(m, __shfl_xor(m, d));
    if ((tid & 63) == 0) red[w] = m;
    __syncthreads();
    m = fmaxf(fmaxf(red[0], red[1]), fmaxf(red[2], red[3]));
    __syncthreads();

    float s = 0.f;
    for (int j = tid; j < NUM_LHS_EMB; j += 256) s += expf(row[j] + bias[j] - m);
    #pragma unroll
    for (int d = 1; d < 64; d <<= 1) s += __shfl_xor(s, d);
    if ((tid & 63) == 0) red[w] = s;
    __syncthreads();
    if (tid == 0) lse[k] = m + logf(red[0] + red[1] + red[2] + red[3]);
}

// ---------------- Kernel B: b-side. wave per l, lane = k ----------------
// v_k = t[k][j_l] - LSE_k ; mb[l] = max_k v_k + bias[j_l] ; ebt[l][k] = exp(v_k - max)
__global__ __launch_bounds__(256) void bside_kernel(
    const float* __restrict__ t, const float* __restrict__ bias,
    const int* __restrict__ lidx, const float* __restrict__ lse,
    ushort* __restrict__ ebt, float* __restrict__ mb) {
    const int l = blockIdx.x * 4 + (threadIdx.x >> 6);
    const int k = threadIdx.x & 63;
    const int j = lidx[l];
    const float v = t[(size_t)k * NUM_LHS_EMB + j] - lse[k];
    float m = v;
    #pragma unroll
    for (int d = 1; d < 64; d <<= 1) m = fmaxf(m, __shfl_xor(m, d));
    ebt[(size_t)l * 64 + k] = f2b(expf(v - m));
    if (k == 0) mb[l] = m + bias[j];
}

// ---------------- Kernel C: a-side. wave per r, lane = k ----------------
// v_k = rts[ridx[r]][k] ; ea[r][k] = exp(v_k - max) ; ma[r] = -log(sum exp(v_k - max))
__global__ __launch_bounds__(256) void aside_kernel(
    const float* __restrict__ rts, const int* __restrict__ ridx,
    ushort* __restrict__ ea, float* __restrict__ ma) {
    const int r = blockIdx.x * 4 + (threadIdx.x >> 6);
    const int k = threadIdx.x & 63;
    const float v = rts[(size_t)ridx[r] * 64 + k];
    float m = v;
    #pragma unroll
    for (int d = 1; d < 64; d <<= 1) m = fmaxf(m, __shfl_xor(m, d));
    const float e = expf(v - m);
    float s = e;
    #pragma unroll
    for (int d = 1; d < 64; d <<= 1) s += __shfl_xor(s, d);
    ea[(size_t)r * 64 + k] = f2b(e);
    if (k == 0) ma[r] = -logf(s);
}

// ---------------- Kernel D: out[l][r] = log( ebt[l,:] . ea[r,:] ) + ma[r] + mb[l] ----
// NT GEMM, K=64, M=NL (rows l), N=NR (cols r). 128x128 block tile, 64x64 per wave.
__global__ __launch_bounds__(256) void gemm_kernel(
    const ushort* __restrict__ A,   // ebt [NL][64]
    const ushort* __restrict__ B,   // ea  [NR][64]
    const float* __restrict__ ma, const float* __restrict__ mb,
    float* __restrict__ out) {
    const int bm = blockIdx.x & 63;
    const int bn = blockIdx.x >> 6;
    const int w = threadIdx.x >> 6, lane = threadIdx.x & 63;
    const int Moff = bm * 128 + (w >> 1) * 64;
    const int Noff = bn * 128 + (w & 1) * 64;
    const int lrow = lane & 15;
    const int lk = (lane >> 4) * 8;

    f32x4 acc[4][4] = {};
    #pragma unroll
    for (int kb = 0; kb < 64; kb += 32) {
        short8 a[4], b[4];
        #pragma unroll
        for (int i = 0; i < 4; i++)
            a[i] = *(const short8*)(A + (size_t)(Moff + i * 16 + lrow) * 64 + kb + lk);
        #pragma unroll
        for (int j = 0; j < 4; j++)
            b[j] = *(const short8*)(B + (size_t)(Noff + j * 16 + lrow) * 64 + kb + lk);
        #pragma unroll
        for (int i = 0; i < 4; i++)
            #pragma unroll
            for (int j = 0; j < 4; j++)
                acc[i][j] = __builtin_amdgcn_mfma_f32_16x16x32_bf16(a[i], b[j], acc[i][j], 0, 0, 0);
    }

    float mav[4];
    #pragma unroll
    for (int j = 0; j < 4; j++) mav[j] = ma[Noff + j * 16 + lrow];
    const int rbase = (lane >> 4) * 4;
    #pragma unroll
    for (int i = 0; i < 4; i++) {
        #pragma unroll
        for (int jr = 0; jr < 4; jr++) {
            const int l_out = Moff + i * 16 + rbase + jr;
            const float mbv = mb[l_out];
            float* __restrict__ orow = out + (size_t)l_out * NR + Noff;
            #pragma unroll
            for (int j = 0; j < 4; j++) {
                orow[j * 16 + lrow] = __logf(acc[i][j][jr]) + mav[j] + mbv;
            }
        }
    }
}

extern "C" void kernel_launch(void* const* d_in, const int* in_sizes, int n_in,
                              void* d_out, int out_size, void* d_ws, size_t ws_size,
                              hipStream_t stream) {
    const float* rts  = (const float*)d_in[0];   // [100000, 64]
    const float* tls  = (const float*)d_in[1];   // [64, 100000]
    const float* bias = (const float*)d_in[2];   // [1, 100000]
    const int* ridx   = (const int*)d_in[3];     // [8192]
    const int* lidx   = (const int*)d_in[4];     // [8192]
    float* out = (float*)d_out;                  // [8192, 8192]

    char* ws = (char*)d_ws;
    float* lse  = (float*)ws;                           // 64 f
    ushort* ea  = (ushort*)(ws + 1024);                 // NR*64 bf16 bits = 1 MB
    ushort* ebt = (ushort*)(ws + 1024 + NR * 64 * 2);   // NL*64 bf16 bits = 1 MB
    float* ma   = (float*)(ws + 1024 + (NR + NL) * 64 * 2);            // NR f
    float* mb   = (float*)(ws + 1024 + (NR + NL) * 64 * 2 + NR * 4);   // NL f

    lse_kernel<<<NUM_TYPES, 256, 0, stream>>>(tls, bias, lse);
    aside_kernel<<<NR / 4, 256, 0, stream>>>(rts, ridx, ea, ma);
    bside_kernel<<<NL / 4, 256, 0, stream>>>(tls, bias, lidx, lse, ebt, mb);
    gemm_kernel<<<(NL / 128) * (NR / 128), 256, 0, stream>>>(ebt, ea, ma, mb, out);
}

// Round 2
// 84.418 us; speedup vs baseline: 2.5579x; 2.5579x over previous
//
#include <hip/hip_runtime.h>
#include <hip/hip_bf16.h>

#define NUM_RHS_EMB 100000
#define NUM_TYPES   64
#define NUM_LHS_EMB 100000
#define NR 8192   // rhs idxs -> output cols
#define NL 8192   // lhs idxs -> output rows
#define LSE_CHUNKS 32
#define LSE_CHUNK  (NUM_LHS_EMB / LSE_CHUNKS)   // 3125

typedef __attribute__((ext_vector_type(8))) short short8;
typedef __attribute__((ext_vector_type(4))) float f32x4;

__device__ __forceinline__ ushort f2b(float x) {
    unsigned u = __builtin_bit_cast(unsigned, x);
    unsigned r = u + 0x7fffu + ((u >> 16) & 1u);   // RNE-ish
    return (ushort)(r >> 16);
}

// ---------------- Kernel A1: partial (max, sum) per (row k, chunk c) ----------------
__global__ __launch_bounds__(256) void lse_part_kernel(
    const float* __restrict__ t, const float* __restrict__ bias, float2* __restrict__ part) {
    const int k = blockIdx.x >> 5;           // type row
    const int c = blockIdx.x & (LSE_CHUNKS - 1);
    const int j0 = c * LSE_CHUNK;
    const float* __restrict__ row = t + (size_t)k * NUM_LHS_EMB + j0;
    const float* __restrict__ b = bias + j0;
    __shared__ float red[4];
    const int tid = threadIdx.x, w = tid >> 6;

    float m = -1e30f;
    for (int j = tid; j < LSE_CHUNK; j += 256) m = fmaxf(m, row[j] + b[j]);
    #pragma unroll
    for (int d = 1; d < 64; d <<= 1) m = fmaxf(m, __shfl_xor(m, d));
    if ((tid & 63) == 0) red[w] = m;
    __syncthreads();
    m = fmaxf(fmaxf(red[0], red[1]), fmaxf(red[2], red[3]));
    __syncthreads();

    float s = 0.f;
    for (int j = tid; j < LSE_CHUNK; j += 256) s += expf(row[j] + b[j] - m);
    #pragma unroll
    for (int d = 1; d < 64; d <<= 1) s += __shfl_xor(s, d);
    if ((tid & 63) == 0) red[w] = s;
    __syncthreads();
    if (tid == 0) part[blockIdx.x] = make_float2(m, red[0] + red[1] + red[2] + red[3]);
}

// ---------------- Kernel A2: combine partials -> lse[k] ----------------
__global__ __launch_bounds__(64) void lse_combine_kernel(
    const float2* __restrict__ part, float* __restrict__ lse) {
    const int k = blockIdx.x;
    const int lane = threadIdx.x;
    float m = -1e30f, s = 0.f;
    if (lane < LSE_CHUNKS) {
        float2 p = part[k * LSE_CHUNKS + lane];
        m = p.x; s = p.y;
    }
    float M = m;
    #pragma unroll
    for (int d = 1; d < 64; d <<= 1) M = fmaxf(M, __shfl_xor(M, d));
    float sc = s * expf(m - M);   // s==0 for idle lanes -> 0
    #pragma unroll
    for (int d = 1; d < 64; d <<= 1) sc += __shfl_xor(sc, d);
    if (lane == 0) lse[k] = M + logf(sc);
}

// ---------------- Kernel B: b-side. wave per l, lane = k ----------------
// v_k = t[k][j_l] - LSE_k ; mb[l] = max_k v_k + bias[j_l] ; ebt[l][k] = exp(v_k - max)
__global__ __launch_bounds__(256) void bside_kernel(
    const float* __restrict__ t, const float* __restrict__ bias,
    const int* __restrict__ lidx, const float* __restrict__ lse,
    ushort* __restrict__ ebt, float* __restrict__ mb) {
    const int l = blockIdx.x * 4 + (threadIdx.x >> 6);
    const int k = threadIdx.x & 63;
    const int j = lidx[l];
    const float v = t[(size_t)k * NUM_LHS_EMB + j] - lse[k];
    float m = v;
    #pragma unroll
    for (int d = 1; d < 64; d <<= 1) m = fmaxf(m, __shfl_xor(m, d));
    ebt[(size_t)l * 64 + k] = f2b(expf(v - m));
    if (k == 0) mb[l] = m + bias[j];
}

// ---------------- Kernel C: a-side. wave per r, lane = k ----------------
__global__ __launch_bounds__(256) void aside_kernel(
    const float* __restrict__ rts, const int* __restrict__ ridx,
    ushort* __restrict__ ea, float* __restrict__ ma) {
    const int r = blockIdx.x * 4 + (threadIdx.x >> 6);
    const int k = threadIdx.x & 63;
    const float v = rts[(size_t)ridx[r] * 64 + k];
    float m = v;
    #pragma unroll
    for (int d = 1; d < 64; d <<= 1) m = fmaxf(m, __shfl_xor(m, d));
    const float e = expf(v - m);
    float s = e;
    #pragma unroll
    for (int d = 1; d < 64; d <<= 1) s += __shfl_xor(s, d);
    ea[(size_t)r * 64 + k] = f2b(e);
    if (k == 0) ma[r] = -logf(s);
}

// ---------------- Kernel D: out[l][r] = log( ebt[l,:] . ea[r,:] ) + ma[r] + mb[l] ----
// NT GEMM, K=64, M=NL (rows l), N=NR (cols r). 128x128 block tile, 64x64 per wave.
__global__ __launch_bounds__(256) void gemm_kernel(
    const ushort* __restrict__ A,   // ebt [NL][64]
    const ushort* __restrict__ B,   // ea  [NR][64]
    const float* __restrict__ ma, const float* __restrict__ mb,
    float* __restrict__ out) {
    const int bm = blockIdx.x & 63;
    const int bn = blockIdx.x >> 6;
    const int w = threadIdx.x >> 6, lane = threadIdx.x & 63;
    const int Moff = bm * 128 + (w >> 1) * 64;
    const int Noff = bn * 128 + (w & 1) * 64;
    const int lrow = lane & 15;
    const int lk = (lane >> 4) * 8;

    f32x4 acc[4][4] = {};
    #pragma unroll
    for (int kb = 0; kb < 64; kb += 32) {
        short8 a[4], b[4];
        #pragma unroll
        for (int i = 0; i < 4; i++)
            a[i] = *(const short8*)(A + (size_t)(Moff + i * 16 + lrow) * 64 + kb + lk);
        #pragma unroll
        for (int j = 0; j < 4; j++)
            b[j] = *(const short8*)(B + (size_t)(Noff + j * 16 + lrow) * 64 + kb + lk);
        #pragma unroll
        for (int i = 0; i < 4; i++)
            #pragma unroll
            for (int j = 0; j < 4; j++)
                acc[i][j] = __builtin_amdgcn_mfma_f32_16x16x32_bf16(a[i], b[j], acc[i][j], 0, 0, 0);
    }

    float mav[4];
    #pragma unroll
    for (int j = 0; j < 4; j++) mav[j] = ma[Noff + j * 16 + lrow];
    const int rbase = (lane >> 4) * 4;
    #pragma unroll
    for (int i = 0; i < 4; i++) {
        #pragma unroll
        for (int jr = 0; jr < 4; jr++) {
            const int l_out = Moff + i * 16 + rbase + jr;
            const float mbv = mb[l_out];
            float* __restrict__ orow = out + (size_t)l_out * NR + Noff;
            #pragma unroll
            for (int j = 0; j < 4; j++) {
                orow[j * 16 + lrow] = __logf(acc[i][j][jr]) + mav[j] + mbv;
            }
        }
    }
}

extern "C" void kernel_launch(void* const* d_in, const int* in_sizes, int n_in,
                              void* d_out, int out_size, void* d_ws, size_t ws_size,
                              hipStream_t stream) {
    const float* rts  = (const float*)d_in[0];   // [100000, 64]
    const float* tls  = (const float*)d_in[1];   // [64, 100000]
    const float* bias = (const float*)d_in[2];   // [1, 100000]
    const int* ridx   = (const int*)d_in[3];     // [8192]
    const int* lidx   = (const int*)d_in[4];     // [8192]
    float* out = (float*)d_out;                  // [8192, 8192]

    char* ws = (char*)d_ws;
    float* lse  = (float*)ws;                           // 64 f
    ushort* ea  = (ushort*)(ws + 1024);                 // NR*64 bf16 bits = 1 MB
    ushort* ebt = (ushort*)(ws + 1024 + NR * 64 * 2);   // NL*64 bf16 bits = 1 MB
    float* ma   = (float*)(ws + 1024 + (NR + NL) * 64 * 2);            // NR f
    float* mb   = (float*)(ws + 1024 + (NR + NL) * 64 * 2 + NR * 4);   // NL f
    float2* part = (float2*)(ws + 1024 + (NR + NL) * 64 * 2 + (NR + NL) * 4); // 2048 float2

    lse_part_kernel<<<NUM_TYPES * LSE_CHUNKS, 256, 0, stream>>>(tls, bias, part);
    lse_combine_kernel<<<NUM_TYPES, 64, 0, stream>>>(part, lse);
    aside_kernel<<<NR / 4, 256, 0, stream>>>(rts, ridx, ea, ma);
    bside_kernel<<<NL / 4, 256, 0, stream>>>(tls, bias, lidx, lse, ebt, mb);
    gemm_kernel<<<(NL / 128) * (NR / 128), 256, 0, stream>>>(ebt, ea, ma, mb, out);
}